// Round 17
// baseline (175.615 us; speedup 1.0000x reference)
//
#include <hip/hip_runtime.h>
#include <hip/hip_bf16.h>

#define BATCH 16384

typedef __attribute__((ext_vector_type(8))) short short8;
typedef __attribute__((ext_vector_type(4))) float f32x4;

typedef const __attribute__((address_space(1))) uint* gas_t;
typedef __attribute__((address_space(3))) uint* las_t;

__device__ __forceinline__ void gl_lds16(const void* g, void* l) {
    __builtin_amdgcn_global_load_lds((gas_t)g, (las_t)l, 16, 0, 0);
}

__device__ __forceinline__ float bf2f(uint u) { union { uint u; float f; } v; v.u = u << 16; return v.f; }
__device__ __forceinline__ ushort f2bf(float f) {   // RNE
    union { float f; uint u; } v; v.f = f;
    uint r = v.u + 0x7fffu + ((v.u >> 16) & 1u);
    return (ushort)(r >> 16);
}
__device__ __forceinline__ uint pack2(float a, float b) { return (uint)f2bf(a) | ((uint)f2bf(b) << 16); }
// truncating bf16 pack of two floats in ONE v_perm_b32
__device__ __forceinline__ uint pack_trunc(float lo, float hi) {
    return __builtin_amdgcn_perm(__float_as_uint(hi), __float_as_uint(lo), 0x07060302u);
}
// fast activations: v_exp_f32 + v_rcp_f32
__device__ __forceinline__ float sigmoidf_(float x) { return __builtin_amdgcn_rcpf(1.0f + __expf(-x)); }
__device__ __forceinline__ float siluf_(float x)    { return x * sigmoidf_(x); }

// XCD-grouping swizzle for grid (128, 4)
__device__ __forceinline__ void xcd_swz(int& bm, int& bn) {
    int lin = blockIdx.x + blockIdx.y * 128;
    int c = lin & 7, s = lin >> 3;
    bm = c * 16 + (s >> 2);
    bn = s & 3;
}

// Uniform cubic B-spline: 8 packed bf16 bases via 128-bit funnel-shift placement.
__device__ __forceinline__ void bases_packed(float x, float g0, float inv_h, uint o[4]) {
    float u = (x - g0) * inv_h;
    float fl = floorf(u);
    float f = u - fl;
    float f2 = f * f, f3 = f2 * f;
    float Ca = f3 * (1.0f / 6.0f);
    float Cb = (1.0f / 6.0f) + 0.5f * (f + f2 - f3);
    float Cc = (2.0f / 3.0f) + 0.5f * f3 - f2;
    float Cd = (1.0f / 6.0f) + 0.5f * (f2 - f) - f3 * (1.0f / 6.0f);
    int t0 = (int)fl;
    t0 = max(-8, min(t0, 19));
    uint dlo = pack_trunc(Cd, Cc);
    uint dhi = pack_trunc(Cb, Ca);
    unsigned long long D = (unsigned long long)dlo | ((unsigned long long)dhi << 32);
    int sp = t0 * 16 - 48;
    unsigned long long l1 = D << (sp & 63);
    unsigned long long r1 = D >> ((-sp) & 63);
    unsigned long long r2 = D >> ((64 - sp) & 63);
    unsigned long long l2 = D << ((sp - 64) & 63);
    unsigned long long lo = (sp >= 0) ? (sp < 64 ? l1 : 0ull) : (sp > -64 ? r1 : 0ull);
    unsigned long long hi = (sp > 0 && sp < 128) ? (sp < 64 ? r2 : l2) : 0ull;
    o[0] = (uint)lo; o[1] = (uint)(lo >> 32); o[2] = (uint)hi; o[3] = (uint)(hi >> 32);
}

// ---------------- merged prep: h-copy + all weight conversions (ONE launch) ----------------
__global__ __launch_bounds__(256) void prep_all(const float* __restrict__ hp,
                                                const float* __restrict__ ip_w, const float* __restrict__ ug_w,
                                                const float* __restrict__ rp,  const float* __restrict__ k2b,
                                                const float* __restrict__ k2s, const float* __restrict__ k2sc,
                                                const float* __restrict__ k1b, const float* __restrict__ k1s,
                                                const float* __restrict__ k1sc,
                                                ushort* __restrict__ acat,
                                                ushort* __restrict__ ipw, ushort* __restrict__ ugw,
                                                ushort* __restrict__ wcat, ushort* __restrict__ w1aug) {
    int t = blockIdx.x * 256 + threadIdx.x;
    if (t < 1048576) {                      // Acat[:,512:1024] = bf16(h_prev)
        int b = t >> 6, j = (t & 63) * 8;
        const float4* s = (const float4*)(hp + (size_t)b * 512 + j);
        float4 a = s[0], c = s[1];
        uint4 o; o.x = pack2(a.x, a.y); o.y = pack2(a.z, a.w); o.z = pack2(c.x, c.y); o.w = pack2(c.z, c.w);
        *(uint4*)(acat + (size_t)b * 1600 + 512 + j) = o;
        return;
    }
    t -= 1048576;
    if (t < 131072) { ipw[t] = f2bf(ip_w[t]); return; }
    t -= 131072;
    if (t < 524288) { ugw[t] = f2bf(ug_w[t]); return; }
    t -= 524288;
    if (t < 819200) {                       // Wcat[512][1600] = [rp_w | k2_base | k2_spline*scaler]
        int n = t / 1600, c = t % 1600; float v;
        if (c < 1024) v = rp[n * 1024 + c];
        else if (c < 1088) v = k2b[n * 64 + (c - 1024)];
        else { int i = (c - 1088) >> 3, k = (c - 1088) & 7; v = k2s[(n * 64 + i) * 8 + k] * k2sc[n * 64 + i]; }
        wcat[t] = f2bf(v); return;
    }
    t -= 819200;
    if (t < 589824) {                       // w1aug[64][9216] = [k1_base | k1_spline*scaler] (plain)
        int n = t / 9216, c = t % 9216; float v;
        if (c < 1024) v = k1b[n * 1024 + c];
        else { int i = (c - 1024) >> 3, k = (c - 1024) & 7; v = k1s[(n * 1024 + i) * 8 + k] * k1sc[n * 1024 + i]; }
        w1aug[t] = f2bf(v);
    }
}

// ---------------- MFMA GEMM (hc): C[m,n] = bf16(A[m,:]·W[n,:]^T + bias[n]) ----------------
__global__ __launch_bounds__(256) void gemm_mfma(const ushort* __restrict__ A, int lda,
                                                 const ushort* __restrict__ Wt, int ldw,
                                                 const float* __restrict__ bias,
                                                 ushort* __restrict__ C, int ldc, int K) {
    __shared__ ushort As[2][128 * 64];
    __shared__ ushort Bs[2][128 * 64];
    const int tid = threadIdx.x;
    const int w = tid >> 6, lane = tid & 63;
    const int fr = lane & 15, fq = lane >> 4;
    int bm, bn; xcd_swz(bm, bn);
    const int m0 = bm * 128, n0 = bn * 128;
    const int wm = w & 1, wn = w >> 1;

    const int srow8 = lane >> 3;
    const int scol  = ((lane & 7) ^ srow8) << 3;
    const ushort* gA[4]; const ushort* gB[4]; int fa[4];
#pragma unroll
    for (int j = 0; j < 4; ++j) {
        int rowj = (j * 4 + w) * 8 + srow8;
        fa[j] = (j * 4 + w) * 512 + lane * 8;
        gA[j] = A  + (size_t)(m0 + rowj) * lda + scol;
        gB[j] = Wt + (size_t)(n0 + rowj) * ldw + scol;
    }
    const int nt = K / 64;
#pragma unroll
    for (int j = 0; j < 4; ++j) {
        gl_lds16(gA[j], &As[0][fa[j]]); gl_lds16(gB[j], &Bs[0][fa[j]]);
        gA[j] += 64; gB[j] += 64;
    }
    f32x4 acc[4][4] = {};
    int cur = 0;
    for (int t = 0; t < nt; ++t) {
        __syncthreads();
        if (t + 1 < nt) {
#pragma unroll
            for (int j = 0; j < 4; ++j) {
                gl_lds16(gA[j], &As[cur ^ 1][fa[j]]); gl_lds16(gB[j], &Bs[cur ^ 1][fa[j]]);
                gA[j] += 64; gB[j] += 64;
            }
        }
#pragma unroll
        for (int s = 0; s < 2; ++s) {
            const int csw = ((s * 4 + fq) ^ (fr & 7)) << 3;
            short8 af[4], bv[4];
#pragma unroll
            for (int mi = 0; mi < 4; ++mi)
                af[mi] = *(const short8*)(&As[cur][(wm * 64 + mi * 16 + fr) * 64 + csw]);
#pragma unroll
            for (int ni = 0; ni < 4; ++ni)
                bv[ni] = *(const short8*)(&Bs[cur][(wn * 64 + ni * 16 + fr) * 64 + csw]);
#pragma unroll
            for (int mi = 0; mi < 4; ++mi)
#pragma unroll
                for (int ni = 0; ni < 4; ++ni)
                    acc[mi][ni] = __builtin_amdgcn_mfma_f32_16x16x32_bf16(af[mi], bv[ni], acc[mi][ni], 0, 0, 0);
        }
        cur ^= 1;
    }
#pragma unroll
    for (int mi = 0; mi < 4; ++mi) {
#pragma unroll
        for (int ni = 0; ni < 4; ++ni) {
            int n = n0 + wn * 64 + ni * 16 + fr;
            float bvs = bias[n];
#pragma unroll
            for (int r = 0; r < 4; ++r) {
                int m = m0 + wm * 64 + mi * 16 + fq * 4 + r;
                C[(size_t)m * ldc + n] = f2bf(acc[mi][ni][r] + bvs);
            }
        }
    }
}

// ---------------- ip GEMM: fp32 A (fused cvt), writes Acat[:,0:512] ----------------
__global__ __launch_bounds__(256) void gemm_ip(const float* __restrict__ X,    // [B][256] fp32
                                               const ushort* __restrict__ Wt,  // [512][256] bf16
                                               const float* __restrict__ bias,
                                               ushort* __restrict__ acat) {    // ld 1600
    __shared__ ushort As[2][128 * 64];
    __shared__ ushort Bs[2][128 * 64];
    const int tid = threadIdx.x;
    const int w = tid >> 6, lane = tid & 63;
    const int fr = lane & 15, fq = lane >> 4;
    int bm, bn; xcd_swz(bm, bn);
    const int m0 = bm * 128, n0 = bn * 128;
    const int wm = w & 1, wn = w >> 1;

    const int srow8 = lane >> 3;
    const int scol = ((lane & 7) ^ srow8) << 3;
    const ushort* gB[4]; int fa[4];
#pragma unroll
    for (int j = 0; j < 4; ++j) {
        int rowj = (j * 4 + w) * 8 + srow8;
        fa[j] = (j * 4 + w) * 512 + lane * 8;
        gB[j] = Wt + (size_t)(n0 + rowj) * 256 + scol;
    }
    const float* gA[4]; int ar[4];
#pragma unroll
    for (int j = 0; j < 4; ++j) {
        int rj = j * 32 + (tid >> 3);
        int lc = (tid & 7) ^ (rj & 7);
        ar[j] = rj * 64 + (tid & 7) * 8;
        gA[j] = X + (size_t)(m0 + rj) * 256 + lc * 8;
    }
    float4 va[4], vb[4];
#pragma unroll
    for (int j = 0; j < 4; ++j) { gl_lds16(gB[j], &Bs[0][fa[j]]); gB[j] += 64; }
#pragma unroll
    for (int j = 0; j < 4; ++j) { va[j] = *(const float4*)gA[j]; vb[j] = *(const float4*)(gA[j] + 4); gA[j] += 64; }
#pragma unroll
    for (int j = 0; j < 4; ++j) {
        uint4 o; o.x = pack2(va[j].x, va[j].y); o.y = pack2(va[j].z, va[j].w);
        o.z = pack2(vb[j].x, vb[j].y); o.w = pack2(vb[j].z, vb[j].w);
        *(uint4*)&As[0][ar[j]] = o;
    }
    f32x4 acc[4][4] = {};
    int cur = 0;
    for (int t = 0; t < 4; ++t) {           // K=256, BK=64
        __syncthreads();
        if (t < 3) {
#pragma unroll
            for (int j = 0; j < 4; ++j) { gl_lds16(gB[j], &Bs[cur ^ 1][fa[j]]); gB[j] += 64; }
#pragma unroll
            for (int j = 0; j < 4; ++j) { va[j] = *(const float4*)gA[j]; vb[j] = *(const float4*)(gA[j] + 4); gA[j] += 64; }
        }
#pragma unroll
        for (int s = 0; s < 2; ++s) {
            const int csw = ((s * 4 + fq) ^ (fr & 7)) << 3;
            short8 af[4], bv[4];
#pragma unroll
            for (int mi = 0; mi < 4; ++mi)
                af[mi] = *(const short8*)(&As[cur][(wm * 64 + mi * 16 + fr) * 64 + csw]);
#pragma unroll
            for (int ni = 0; ni < 4; ++ni)
                bv[ni] = *(const short8*)(&Bs[cur][(wn * 64 + ni * 16 + fr) * 64 + csw]);
#pragma unroll
            for (int mi = 0; mi < 4; ++mi)
#pragma unroll
                for (int ni = 0; ni < 4; ++ni)
                    acc[mi][ni] = __builtin_amdgcn_mfma_f32_16x16x32_bf16(af[mi], bv[ni], acc[mi][ni], 0, 0, 0);
        }
        if (t < 3) {
#pragma unroll
            for (int j = 0; j < 4; ++j) {
                uint4 o; o.x = pack2(va[j].x, va[j].y); o.y = pack2(va[j].z, va[j].w);
                o.z = pack2(vb[j].x, vb[j].y); o.w = pack2(vb[j].z, vb[j].w);
                *(uint4*)&As[cur ^ 1][ar[j]] = o;
            }
        }
        cur ^= 1;
    }
#pragma unroll
    for (int mi = 0; mi < 4; ++mi) {
#pragma unroll
        for (int ni = 0; ni < 4; ++ni) {
            int n = n0 + wn * 64 + ni * 16 + fr;
            float bvs = bias[n];
#pragma unroll
            for (int r = 0; r < 4; ++r) {
                int m = m0 + wm * 64 + mi * 16 + fq * 4 + r;
                acat[(size_t)m * 1600 + n] = f2bf(acc[mi][ni][r] + bvs);
            }
        }
    }
}

// ---------------- MERGED kan1 ∥ ug: homogeneous 32KB-LDS blocks, interleaved 4:1 ----------------
// blockIdx.x % 5 == 0  -> ug GEMM block (BK=32 dbuf, 512 blocks)
// else                 -> kan1 block (2048 blocks: m-block = id&255, kb = id>>8)
__global__ __launch_bounds__(256) void kan1_ug(const ushort* __restrict__ acat,   // [B][1600]
                                               const ushort* __restrict__ w1aug,  // [64][9216] plain
                                               const float* __restrict__ grid1,
                                               ushort* __restrict__ midp,         // 8x[B][64] bf16
                                               const ushort* __restrict__ ugw,    // [512][1024]
                                               const float* __restrict__ ug_b,
                                               ushort* __restrict__ ug_bf) {      // [B][512]
    __shared__ ushort As[2][4096];
    __shared__ ushort Bs[2][4096];
    const int tid = threadIdx.x;
    const int lin = blockIdx.x;
    const int w = tid >> 6, lane = tid & 63;
    const int fr = lane & 15, fq = lane >> 4;
    const int wm = w & 1, wn = w >> 1;

    if (lin % 5 == 0) {
        // ================= ug GEMM, 128x128 tile, BK=32, dbuf (32 KB LDS) =================
        const int g = lin / 5;                        // 0..511
        const int m0 = (g & 127) * 128, n0 = (g >> 7) * 128;
        const int r0 = tid >> 2, r1 = 64 + (tid >> 2), pc = tid & 3;
        const int lc0 = (pc ^ ((r0 >> 1) & 3)) << 3;  // pre-swizzled source chunk
        const int lc1 = (pc ^ ((r1 >> 1) & 3)) << 3;
        const int fa0 = tid * 8, fa1 = (tid + 256) * 8;
        const ushort* gA0 = acat + (size_t)(m0 + r0) * 1600 + lc0;
        const ushort* gA1 = acat + (size_t)(m0 + r1) * 1600 + lc1;
        const ushort* gB0 = ugw  + (size_t)(n0 + r0) * 1024 + lc0;
        const ushort* gB1 = ugw  + (size_t)(n0 + r1) * 1024 + lc1;
        gl_lds16(gA0, &As[0][fa0]); gl_lds16(gA1, &As[0][fa1]);
        gl_lds16(gB0, &Bs[0][fa0]); gl_lds16(gB1, &Bs[0][fa1]);
        gA0 += 32; gA1 += 32; gB0 += 32; gB1 += 32;
        f32x4 acc[4][4] = {};
        int cur = 0;
        for (int t = 0; t < 32; ++t) {                // K=1024
            __syncthreads();
            if (t + 1 < 32) {
                gl_lds16(gA0, &As[cur ^ 1][fa0]); gl_lds16(gA1, &As[cur ^ 1][fa1]);
                gl_lds16(gB0, &Bs[cur ^ 1][fa0]); gl_lds16(gB1, &Bs[cur ^ 1][fa1]);
                gA0 += 32; gA1 += 32; gB0 += 32; gB1 += 32;
            }
            short8 af[4], bv[4];
#pragma unroll
            for (int mi = 0; mi < 4; ++mi) {
                int row = wm * 64 + mi * 16 + fr;
                af[mi] = *(const short8*)(&As[cur][row * 32 + ((fq ^ ((row >> 1) & 3)) << 3)]);
            }
#pragma unroll
            for (int ni = 0; ni < 4; ++ni) {
                int row = wn * 64 + ni * 16 + fr;
                bv[ni] = *(const short8*)(&Bs[cur][row * 32 + ((fq ^ ((row >> 1) & 3)) << 3)]);
            }
#pragma unroll
            for (int mi = 0; mi < 4; ++mi)
#pragma unroll
                for (int ni = 0; ni < 4; ++ni)
                    acc[mi][ni] = __builtin_amdgcn_mfma_f32_16x16x32_bf16(af[mi], bv[ni], acc[mi][ni], 0, 0, 0);
            cur ^= 1;
        }
#pragma unroll
        for (int mi = 0; mi < 4; ++mi) {
#pragma unroll
            for (int ni = 0; ni < 4; ++ni) {
                int n = n0 + wn * 64 + ni * 16 + fr;
                float bvs = ug_b[n];
#pragma unroll
                for (int r = 0; r < 4; ++r) {
                    int m = m0 + wm * 64 + mi * 16 + fq * 4 + r;
                    ug_bf[(size_t)m * 512 + n] = f2bf(acc[mi][ni][r] + bvs);
                }
            }
        }
        return;
    }

    // ================= kan1 block (r16 structure) =================
    const int id = lin - 1 - lin / 5;                 // 0..2047
    const int m0 = (id & 255) * 64;
    const int kb = id >> 8;                           // 0..7
    const float g0 = grid1[0];
    const float inv_h = 1.0f / (grid1[1] - g0);

    const int srow = tid >> 3, sc = tid & 7;
    const int lc8 = (sc ^ (srow & 7)) << 3;
    const ushort* wB0  = w1aug + (size_t)srow * 9216 + lc8;
    const ushort* wB1  = w1aug + (size_t)(srow + 32) * 9216 + lc8;
    const int wpo = srow * 64 + lc8;
    const int cB = kb * 128;                          // silu K base (2 steps of 64)
    const int bB = 1024 + kb * 1024;                  // bases K base (16 steps of 64)

    const ushort* aR0 = acat + (size_t)(m0 + srow) * 1600;
    const ushort* aR1 = acat + (size_t)(m0 + srow + 32) * 1600;

    uint4 sA0[2], sA1[2];
#pragma unroll
    for (int s = 0; s < 2; ++s) {
        sA0[s] = *(const uint4*)(aR0 + cB + s * 64 + sc * 8);
        sA1[s] = *(const uint4*)(aR1 + cB + s * 64 + sc * 8);
    }
    uint xa[16], xb[16];
#pragma unroll
    for (int bs = 0; bs < 16; ++bs) {
        xa[bs] = aR0[cB + bs * 8 + sc];
        xb[bs] = aR1[cB + bs * 8 + sc];
    }

    f32x4 acc[2][2] = {};
    auto stageB = [&](int c, int buf) {
        gl_lds16(wB0 + c, &Bs[buf][tid * 8]);
        gl_lds16(wB1 + c, &Bs[buf][2048 + tid * 8]);
    };
    auto stageAsilu = [&](int s, int buf) {
        uint r0[4] = {sA0[s].x, sA0[s].y, sA0[s].z, sA0[s].w};
        uint r1[4] = {sA1[s].x, sA1[s].y, sA1[s].z, sA1[s].w};
        uint o0[4], o1[4];
#pragma unroll
        for (int p = 0; p < 4; ++p) {
            o0[p] = pack_trunc(siluf_(bf2f(r0[p] & 0xffffu)), siluf_(bf2f(r0[p] >> 16)));
            o1[p] = pack_trunc(siluf_(bf2f(r1[p] & 0xffffu)), siluf_(bf2f(r1[p] >> 16)));
        }
        uint4 q0; q0.x = o0[0]; q0.y = o0[1]; q0.z = o0[2]; q0.w = o0[3];
        uint4 q1; q1.x = o1[0]; q1.y = o1[1]; q1.z = o1[2]; q1.w = o1[3];
        *(uint4*)&As[buf][wpo] = q0;
        *(uint4*)&As[buf][2048 + wpo] = q1;
    };
    auto stageAbases = [&](uint x0u, uint x1u, int buf) {
        uint o0[4], o1[4];
        bases_packed(bf2f(x0u), g0, inv_h, o0);
        bases_packed(bf2f(x1u), g0, inv_h, o1);
        uint4 q0; q0.x = o0[0]; q0.y = o0[1]; q0.z = o0[2]; q0.w = o0[3];
        uint4 q1; q1.x = o1[0]; q1.y = o1[1]; q1.z = o1[2]; q1.w = o1[3];
        *(uint4*)&As[buf][wpo] = q0;
        *(uint4*)&As[buf][2048 + wpo] = q1;
    };
    auto mfma_step = [&](int buf) {
        __builtin_amdgcn_s_setprio(1);               // T5
#pragma unroll
        for (int s2 = 0; s2 < 2; ++s2) {
            short8 af[2], bv[2];
#pragma unroll
            for (int mi = 0; mi < 2; ++mi) {
                int arow = wm * 32 + mi * 16 + fr;
                af[mi] = *(const short8*)(&As[buf][arow * 64 + (((s2 * 4 + fq) ^ (arow & 7)) << 3)]);
            }
#pragma unroll
            for (int ni = 0; ni < 2; ++ni) {
                int brow = wn * 32 + ni * 16 + fr;
                bv[ni] = *(const short8*)(&Bs[buf][brow * 64 + (((s2 * 4 + fq) ^ (brow & 7)) << 3)]);
            }
#pragma unroll
            for (int mi = 0; mi < 2; ++mi)
#pragma unroll
                for (int ni = 0; ni < 2; ++ni)
                    acc[mi][ni] = __builtin_amdgcn_mfma_f32_16x16x32_bf16(af[mi], bv[ni], acc[mi][ni], 0, 0, 0);
        }
        __builtin_amdgcn_s_setprio(0);
    };

    stageB(cB, 0); stageAsilu(0, 0);
    __syncthreads();
    stageB(cB + 64, 1); stageAsilu(1, 1);
    mfma_step(0);
    __syncthreads();
    stageB(bB, 0); stageAbases(xa[0], xb[0], 0);
    mfma_step(1);
#pragma unroll
    for (int bs = 0; bs < 15; ++bs) {
        __syncthreads();
        stageB(bB + (bs + 1) * 64, (bs + 1) & 1);
        stageAbases(xa[bs + 1], xb[bs + 1], (bs + 1) & 1);
        mfma_step(bs & 1);
    }
    __syncthreads();
    mfma_step(1);

    ushort* outp = midp + (size_t)kb * (BATCH * 64);
#pragma unroll
    for (int mi = 0; mi < 2; ++mi)
#pragma unroll
        for (int ni = 0; ni < 2; ++ni)
#pragma unroll
            for (int r = 0; r < 4; ++r)
                outp[(size_t)(m0 + wm * 32 + mi * 16 + fq * 4 + r) * 64 + wn * 32 + ni * 16 + fr] = f2bf(acc[mi][ni][r]);
}

// ---------------- Acat[:,1024:1600] = [silu(mid) | bases(mid)], 8 bf16 partials, 4 elems/thread ----------------
__global__ __launch_bounds__(256) void bs2_kernel(const ushort* __restrict__ midp,
                                                  const float* __restrict__ grid2,
                                                  ushort* __restrict__ acat) {
    int t4 = blockIdx.x * 256 + threadIdx.x;    // over B*16
    if (t4 >= BATCH * 16) return;
    int base = t4 * 4;
    float xs[4] = {0.f, 0.f, 0.f, 0.f};
#pragma unroll
    for (int p = 0; p < 8; ++p) {
        uint2 v = *(const uint2*)(midp + (size_t)p * (BATCH * 64) + base);
        xs[0] += bf2f(v.x & 0xffffu); xs[1] += bf2f(v.x >> 16);
        xs[2] += bf2f(v.y & 0xffffu); xs[3] += bf2f(v.y >> 16);
    }
    int b = base >> 6, i = base & 63;
    float g0 = grid2[0], inv_h = 1.0f / (grid2[1] - g0);
    uint2 sil;
    sil.x = pack2(siluf_(xs[0]), siluf_(xs[1]));
    sil.y = pack2(siluf_(xs[2]), siluf_(xs[3]));
    *(uint2*)&acat[(size_t)b * 1600 + 1024 + i] = sil;
#pragma unroll
    for (int e = 0; e < 4; ++e) {
        uint o[4];
        bases_packed(xs[e], g0, inv_h, o);
        uint4 o4; o4.x = o[0]; o4.y = o[1]; o4.z = o[2]; o4.w = o[3];
        *(uint4*)&acat[(size_t)b * 1600 + 1088 + (i + e) * 8] = o4;
    }
}

// ---------------- fused gate + double-LN + blend ----------------
__device__ __forceinline__ void block_reduce_2(float& a, float& b, float (*red)[4]) {
#pragma unroll
    for (int off = 32; off; off >>= 1) {
        a += __shfl_xor(a, off, 64);
        b += __shfl_xor(b, off, 64);
    }
    int lane = threadIdx.x & 63, wid = threadIdx.x >> 6;
    if (lane == 0) { red[0][wid] = a; red[1][wid] = b; }
    __syncthreads();
    a = red[0][0] + red[0][1] + red[0][2] + red[0][3];
    b = red[1][0] + red[1][1] + red[1][2] + red[1][3];
}

__global__ __launch_bounds__(256) void final2(const ushort* __restrict__ ug,
                                              const ushort* __restrict__ hcb,
                                              const ushort* __restrict__ acat,   // h_prev bf16 at cols 512:1024
                                              const float* __restrict__ ug_g,
                                              const float* __restrict__ ug_beta,
                                              const float* __restrict__ cg,
                                              const float* __restrict__ cb,
                                              float* __restrict__ out) {
    int row = blockIdx.x, tid = threadIdx.x;
    __shared__ float rA[2][4], rB[2][4], rC[2][4];
    float u0 = bf2f((uint)ug[(size_t)row * 512 + tid]);
    float u1 = bf2f((uint)ug[(size_t)row * 512 + tid + 256]);
    float h0 = bf2f((uint)hcb[(size_t)row * 512 + tid]);
    float h1 = bf2f((uint)hcb[(size_t)row * 512 + tid + 256]);
    float hp0 = bf2f((uint)acat[(size_t)row * 1600 + 512 + tid]);
    float hp1 = bf2f((uint)acat[(size_t)row * 1600 + 768 + tid]);
    float s = u0 + u1, ss = u0 * u0 + u1 * u1;
    block_reduce_2(s, ss, rA);
    float mu = s * (1.0f / 512.0f);
    float var = ss * (1.0f / 512.0f) - mu * mu;
    float r = rsqrtf(var + 1e-5f);
    float uu0 = sigmoidf_((u0 - mu) * r * ug_g[tid] + ug_beta[tid]);
    float uu1 = sigmoidf_((u1 - mu) * r * ug_g[tid + 256] + ug_beta[tid + 256]);
    float cg0 = cg[tid], cg1 = cg[tid + 256], cb0 = cb[tid], cb1 = cb[tid + 256];
    float s2 = h0 + h1, ss2 = h0 * h0 + h1 * h1;
    block_reduce_2(s2, ss2, rB);
    float mu2 = s2 * (1.0f / 512.0f);
    float var2 = ss2 * (1.0f / 512.0f) - mu2 * mu2;
    float r2 = rsqrtf(var2 + 1e-5f);
    float w0 = (h0 - mu2) * r2 * cg0 + cb0;
    float w1 = (h1 - mu2) * r2 * cg1 + cb1;
    float s3 = w0 + w1, ss3 = w0 * w0 + w1 * w1;
    block_reduce_2(s3, ss3, rC);
    float mu3 = s3 * (1.0f / 512.0f);
    float var3 = ss3 * (1.0f / 512.0f) - mu3 * mu3;
    float r3 = rsqrtf(var3 + 1e-5f);
    float c0 = siluf_((w0 - mu3) * r3 * cg0 + cb0);
    float c1 = siluf_((w1 - mu3) * r3 * cg1 + cb1);
    size_t o0 = (size_t)row * 512 + tid, o1 = o0 + 256;
    out[o0] = (1.0f - uu0) * hp0 + uu0 * c0;
    out[o1] = (1.0f - uu1) * hp1 + uu1 * c1;
}

extern "C" void kernel_launch(void* const* d_in, const int* in_sizes, int n_in,
                              void* d_out, int out_size, void* d_ws, size_t ws_size,
                              hipStream_t stream) {
    const float* x        = (const float*)d_in[0];
    const float* h_prev   = (const float*)d_in[1];
    const float* ip_w     = (const float*)d_in[2];
    const float* ip_b     = (const float*)d_in[3];
    // d_in[4..7] rg_* : dead (reset gate unused in h_t)
    const float* ug_w     = (const float*)d_in[8];
    const float* ug_b     = (const float*)d_in[9];
    const float* ug_g     = (const float*)d_in[10];
    const float* ug_beta  = (const float*)d_in[11];
    const float* k1_base  = (const float*)d_in[12];
    const float* k1_spline= (const float*)d_in[13];
    const float* k1_scaler= (const float*)d_in[14];
    const float* grid1    = (const float*)d_in[15];
    const float* k2_base  = (const float*)d_in[16];
    const float* k2_spline= (const float*)d_in[17];
    const float* k2_scaler= (const float*)d_in[18];
    const float* grid2    = (const float*)d_in[19];
    const float* cn_g     = (const float*)d_in[20];
    const float* cn_b     = (const float*)d_in[21];
    const float* rp_w     = (const float*)d_in[22];
    const float* rp_b     = (const float*)d_in[23];
    float* out = (float*)d_out;
    char* W = (char*)d_ws;

    ushort* Acat    = (ushort*)(W);                   // 52,428,800 B  [B][1600]
    ushort* ug_bf   = (ushort*)(W + 52428800);        // 16,777,216 B  [B][512]
    ushort* midp    = (ushort*)(W + 69206016);        // 16,777,216 B  8x[B][64] bf16
    ushort* hc_bf   = (ushort*)(W + 102760448);       // 16,777,216 B  [B][512]
    ushort* ipw_bf  = (ushort*)(W + 136314880);       //    262,144 B
    ushort* ugw_bf  = (ushort*)(W + 136577024);       //  1,048,576 B
    ushort* wcat    = (ushort*)(W + 137625600);       //  1,638,400 B  [512][1600]
    ushort* w1aug   = (ushort*)(W + 139264000);       //  1,179,648 B  (plain)

    // --- prep: h-copy + all weight conversions in ONE launch ---
    hipLaunchKernelGGL(prep_all, dim3(12160), dim3(256), 0, stream,
                       h_prev, ip_w, ug_w, rp_w, k2_base, k2_spline, k2_scaler,
                       k1_base, k1_spline, k1_scaler,
                       Acat, ipw_bf, ugw_bf, wcat, w1aug);

    // --- Acat[:,0:512] = bf16(x @ ip_w.T + ip_b) ---
    hipLaunchKernelGGL(gemm_ip, dim3(BATCH / 128, 4), dim3(256), 0, stream,
                       x, ipw_bf, ip_b, Acat);

    // --- KAN1 ∥ ug GEMM (merged, interleaved 4:1, homogeneous 32KB LDS) ---
    hipLaunchKernelGGL(kan1_ug, dim3(2560), dim3(256), 0, stream,
                       Acat, w1aug, grid1, midp, ugw_bf, ug_b, ug_bf);

    // --- bs2: midp -> Acat[:,1024:1600] ---
    hipLaunchKernelGGL(bs2_kernel, dim3(BATCH * 16 / 256), dim3(256), 0, stream, midp, grid2, Acat);

    // --- hc = bf16(Acat @ Wcat.T + rp_b)  (residual + KAN2 in one GEMM) ---
    hipLaunchKernelGGL(gemm_mfma, dim3(BATCH / 128, 4), dim3(256), 0, stream,
                       Acat, 1600, wcat, 1600, rp_b, hc_bf, 512, 1600);

    // --- h_t ---
    hipLaunchKernelGGL(final2, dim3(BATCH), dim3(256), 0, stream, ug_bf, hc_bf, Acat, ug_g, ug_beta, cn_g, cn_b, out);
}

// Round 18
// 158.851 us; speedup vs baseline: 1.1055x; 1.1055x over previous
//
#include <hip/hip_runtime.h>
#include <hip/hip_bf16.h>

#define BATCH 16384

typedef __attribute__((ext_vector_type(8))) short short8;
typedef __attribute__((ext_vector_type(4))) float f32x4;

typedef const __attribute__((address_space(1))) uint* gas_t;
typedef __attribute__((address_space(3))) uint* las_t;

__device__ __forceinline__ void gl_lds16(const void* g, void* l) {
    __builtin_amdgcn_global_load_lds((gas_t)g, (las_t)l, 16, 0, 0);
}

__device__ __forceinline__ float bf2f(uint u) { union { uint u; float f; } v; v.u = u << 16; return v.f; }
__device__ __forceinline__ ushort f2bf(float f) {   // RNE
    union { float f; uint u; } v; v.f = f;
    uint r = v.u + 0x7fffu + ((v.u >> 16) & 1u);
    return (ushort)(r >> 16);
}
__device__ __forceinline__ uint pack2(float a, float b) { return (uint)f2bf(a) | ((uint)f2bf(b) << 16); }
// truncating bf16 pack of two floats in ONE v_perm_b32
__device__ __forceinline__ uint pack_trunc(float lo, float hi) {
    return __builtin_amdgcn_perm(__float_as_uint(hi), __float_as_uint(lo), 0x07060302u);
}
// fast activations: v_exp_f32 + v_rcp_f32
__device__ __forceinline__ float sigmoidf_(float x) { return __builtin_amdgcn_rcpf(1.0f + __expf(-x)); }
__device__ __forceinline__ float siluf_(float x)    { return x * sigmoidf_(x); }

// XCD-grouping swizzle for grid (128, 4)
__device__ __forceinline__ void xcd_swz(int& bm, int& bn) {
    int lin = blockIdx.x + blockIdx.y * 128;
    int c = lin & 7, s = lin >> 3;
    bm = c * 16 + (s >> 2);
    bn = s & 3;
}

// Uniform cubic B-spline: 8 packed bf16 bases via 128-bit funnel-shift placement.
__device__ __forceinline__ void bases_packed(float x, float g0, float inv_h, uint o[4]) {
    float u = (x - g0) * inv_h;
    float fl = floorf(u);
    float f = u - fl;
    float f2 = f * f, f3 = f2 * f;
    float Ca = f3 * (1.0f / 6.0f);
    float Cb = (1.0f / 6.0f) + 0.5f * (f + f2 - f3);
    float Cc = (2.0f / 3.0f) + 0.5f * f3 - f2;
    float Cd = (1.0f / 6.0f) + 0.5f * (f2 - f) - f3 * (1.0f / 6.0f);
    int t0 = (int)fl;
    t0 = max(-8, min(t0, 19));
    uint dlo = pack_trunc(Cd, Cc);
    uint dhi = pack_trunc(Cb, Ca);
    unsigned long long D = (unsigned long long)dlo | ((unsigned long long)dhi << 32);
    int sp = t0 * 16 - 48;
    unsigned long long l1 = D << (sp & 63);
    unsigned long long r1 = D >> ((-sp) & 63);
    unsigned long long r2 = D >> ((64 - sp) & 63);
    unsigned long long l2 = D << ((sp - 64) & 63);
    unsigned long long lo = (sp >= 0) ? (sp < 64 ? l1 : 0ull) : (sp > -64 ? r1 : 0ull);
    unsigned long long hi = (sp > 0 && sp < 128) ? (sp < 64 ? r2 : l2) : 0ull;
    o[0] = (uint)lo; o[1] = (uint)(lo >> 32); o[2] = (uint)hi; o[3] = (uint)(hi >> 32);
}

// ---------------- merged prep: h-copy + all weight conversions (ONE launch) ----------------
__global__ __launch_bounds__(256) void prep_all(const float* __restrict__ hp,
                                                const float* __restrict__ ip_w, const float* __restrict__ ug_w,
                                                const float* __restrict__ rp,  const float* __restrict__ k2b,
                                                const float* __restrict__ k2s, const float* __restrict__ k2sc,
                                                const float* __restrict__ k1b, const float* __restrict__ k1s,
                                                const float* __restrict__ k1sc,
                                                ushort* __restrict__ acat,
                                                ushort* __restrict__ ipw, ushort* __restrict__ ugw,
                                                ushort* __restrict__ wcat, ushort* __restrict__ w1aug) {
    int t = blockIdx.x * 256 + threadIdx.x;
    if (t < 1048576) {                      // Acat[:,512:1024] = bf16(h_prev)
        int b = t >> 6, j = (t & 63) * 8;
        const float4* s = (const float4*)(hp + (size_t)b * 512 + j);
        float4 a = s[0], c = s[1];
        uint4 o; o.x = pack2(a.x, a.y); o.y = pack2(a.z, a.w); o.z = pack2(c.x, c.y); o.w = pack2(c.z, c.w);
        *(uint4*)(acat + (size_t)b * 1600 + 512 + j) = o;
        return;
    }
    t -= 1048576;
    if (t < 131072) { ipw[t] = f2bf(ip_w[t]); return; }
    t -= 131072;
    if (t < 524288) { ugw[t] = f2bf(ug_w[t]); return; }
    t -= 524288;
    if (t < 819200) {                       // Wcat[512][1600] = [rp_w | k2_base | k2_spline*scaler]
        int n = t / 1600, c = t % 1600; float v;
        if (c < 1024) v = rp[n * 1024 + c];
        else if (c < 1088) v = k2b[n * 64 + (c - 1024)];
        else { int i = (c - 1088) >> 3, k = (c - 1088) & 7; v = k2s[(n * 64 + i) * 8 + k] * k2sc[n * 64 + i]; }
        wcat[t] = f2bf(v); return;
    }
    t -= 819200;
    if (t < 589824) {                       // w1aug[64][9216] = [k1_base | k1_spline*scaler] (plain)
        int n = t / 9216, c = t % 9216; float v;
        if (c < 1024) v = k1b[n * 1024 + c];
        else { int i = (c - 1024) >> 3, k = (c - 1024) & 7; v = k1s[(n * 1024 + i) * 8 + k] * k1sc[n * 1024 + i]; }
        w1aug[t] = f2bf(v);
    }
}

// ---------------- MFMA GEMM: C[m,n] = bf16(A[m,:]·W[n,:]^T + bias[n]) ----------------
__global__ __launch_bounds__(256) void gemm_mfma(const ushort* __restrict__ A, int lda,
                                                 const ushort* __restrict__ Wt, int ldw,
                                                 const float* __restrict__ bias,
                                                 ushort* __restrict__ C, int ldc, int K) {
    __shared__ ushort As[2][128 * 64];
    __shared__ ushort Bs[2][128 * 64];
    const int tid = threadIdx.x;
    const int w = tid >> 6, lane = tid & 63;
    const int fr = lane & 15, fq = lane >> 4;
    int bm, bn; xcd_swz(bm, bn);
    const int m0 = bm * 128, n0 = bn * 128;
    const int wm = w & 1, wn = w >> 1;

    const int srow8 = lane >> 3;
    const int scol  = ((lane & 7) ^ srow8) << 3;
    const ushort* gA[4]; const ushort* gB[4]; int fa[4];
#pragma unroll
    for (int j = 0; j < 4; ++j) {
        int rowj = (j * 4 + w) * 8 + srow8;
        fa[j] = (j * 4 + w) * 512 + lane * 8;
        gA[j] = A  + (size_t)(m0 + rowj) * lda + scol;
        gB[j] = Wt + (size_t)(n0 + rowj) * ldw + scol;
    }
    const int nt = K / 64;
#pragma unroll
    for (int j = 0; j < 4; ++j) {
        gl_lds16(gA[j], &As[0][fa[j]]); gl_lds16(gB[j], &Bs[0][fa[j]]);
        gA[j] += 64; gB[j] += 64;
    }
    f32x4 acc[4][4] = {};
    int cur = 0;
    for (int t = 0; t < nt; ++t) {
        __syncthreads();
        if (t + 1 < nt) {
#pragma unroll
            for (int j = 0; j < 4; ++j) {
                gl_lds16(gA[j], &As[cur ^ 1][fa[j]]); gl_lds16(gB[j], &Bs[cur ^ 1][fa[j]]);
                gA[j] += 64; gB[j] += 64;
            }
        }
#pragma unroll
        for (int s = 0; s < 2; ++s) {
            const int csw = ((s * 4 + fq) ^ (fr & 7)) << 3;
            short8 af[4], bv[4];
#pragma unroll
            for (int mi = 0; mi < 4; ++mi)
                af[mi] = *(const short8*)(&As[cur][(wm * 64 + mi * 16 + fr) * 64 + csw]);
#pragma unroll
            for (int ni = 0; ni < 4; ++ni)
                bv[ni] = *(const short8*)(&Bs[cur][(wn * 64 + ni * 16 + fr) * 64 + csw]);
#pragma unroll
            for (int mi = 0; mi < 4; ++mi)
#pragma unroll
                for (int ni = 0; ni < 4; ++ni)
                    acc[mi][ni] = __builtin_amdgcn_mfma_f32_16x16x32_bf16(af[mi], bv[ni], acc[mi][ni], 0, 0, 0);
        }
        cur ^= 1;
    }
#pragma unroll
    for (int mi = 0; mi < 4; ++mi) {
#pragma unroll
        for (int ni = 0; ni < 4; ++ni) {
            int n = n0 + wn * 64 + ni * 16 + fr;
            float bvs = bias[n];
#pragma unroll
            for (int r = 0; r < 4; ++r) {
                int m = m0 + wm * 64 + mi * 16 + fq * 4 + r;
                C[(size_t)m * ldc + n] = f2bf(acc[mi][ni][r] + bvs);
            }
        }
    }
}

// ---------------- ip GEMM: fp32 A (fused cvt), writes Acat[:,0:512] ----------------
__global__ __launch_bounds__(256) void gemm_ip(const float* __restrict__ X,    // [B][256] fp32
                                               const ushort* __restrict__ Wt,  // [512][256] bf16
                                               const float* __restrict__ bias,
                                               ushort* __restrict__ acat) {    // ld 1600
    __shared__ ushort As[2][128 * 64];
    __shared__ ushort Bs[2][128 * 64];
    const int tid = threadIdx.x;
    const int w = tid >> 6, lane = tid & 63;
    const int fr = lane & 15, fq = lane >> 4;
    int bm, bn; xcd_swz(bm, bn);
    const int m0 = bm * 128, n0 = bn * 128;
    const int wm = w & 1, wn = w >> 1;

    const int srow8 = lane >> 3;
    const int scol = ((lane & 7) ^ srow8) << 3;
    const ushort* gB[4]; int fa[4];
#pragma unroll
    for (int j = 0; j < 4; ++j) {
        int rowj = (j * 4 + w) * 8 + srow8;
        fa[j] = (j * 4 + w) * 512 + lane * 8;
        gB[j] = Wt + (size_t)(n0 + rowj) * 256 + scol;
    }
    const float* gA[4]; int ar[4];
#pragma unroll
    for (int j = 0; j < 4; ++j) {
        int rj = j * 32 + (tid >> 3);
        int lc = (tid & 7) ^ (rj & 7);
        ar[j] = rj * 64 + (tid & 7) * 8;
        gA[j] = X + (size_t)(m0 + rj) * 256 + lc * 8;
    }
    float4 va[4], vb[4];
#pragma unroll
    for (int j = 0; j < 4; ++j) { gl_lds16(gB[j], &Bs[0][fa[j]]); gB[j] += 64; }
#pragma unroll
    for (int j = 0; j < 4; ++j) { va[j] = *(const float4*)gA[j]; vb[j] = *(const float4*)(gA[j] + 4); gA[j] += 64; }
#pragma unroll
    for (int j = 0; j < 4; ++j) {
        uint4 o; o.x = pack2(va[j].x, va[j].y); o.y = pack2(va[j].z, va[j].w);
        o.z = pack2(vb[j].x, vb[j].y); o.w = pack2(vb[j].z, vb[j].w);
        *(uint4*)&As[0][ar[j]] = o;
    }
    f32x4 acc[4][4] = {};
    int cur = 0;
    for (int t = 0; t < 4; ++t) {           // K=256, BK=64
        __syncthreads();
        if (t < 3) {
#pragma unroll
            for (int j = 0; j < 4; ++j) { gl_lds16(gB[j], &Bs[cur ^ 1][fa[j]]); gB[j] += 64; }
#pragma unroll
            for (int j = 0; j < 4; ++j) { va[j] = *(const float4*)gA[j]; vb[j] = *(const float4*)(gA[j] + 4); gA[j] += 64; }
        }
#pragma unroll
        for (int s = 0; s < 2; ++s) {
            const int csw = ((s * 4 + fq) ^ (fr & 7)) << 3;
            short8 af[4], bv[4];
#pragma unroll
            for (int mi = 0; mi < 4; ++mi)
                af[mi] = *(const short8*)(&As[cur][(wm * 64 + mi * 16 + fr) * 64 + csw]);
#pragma unroll
            for (int ni = 0; ni < 4; ++ni)
                bv[ni] = *(const short8*)(&Bs[cur][(wn * 64 + ni * 16 + fr) * 64 + csw]);
#pragma unroll
            for (int mi = 0; mi < 4; ++mi)
#pragma unroll
                for (int ni = 0; ni < 4; ++ni)
                    acc[mi][ni] = __builtin_amdgcn_mfma_f32_16x16x32_bf16(af[mi], bv[ni], acc[mi][ni], 0, 0, 0);
        }
        if (t < 3) {
#pragma unroll
            for (int j = 0; j < 4; ++j) {
                uint4 o; o.x = pack2(va[j].x, va[j].y); o.y = pack2(va[j].z, va[j].w);
                o.z = pack2(vb[j].x, vb[j].y); o.w = pack2(vb[j].z, vb[j].w);
                *(uint4*)&As[cur ^ 1][ar[j]] = o;
            }
        }
        cur ^= 1;
    }
#pragma unroll
    for (int mi = 0; mi < 4; ++mi) {
#pragma unroll
        for (int ni = 0; ni < 4; ++ni) {
            int n = n0 + wn * 64 + ni * 16 + fr;
            float bvs = bias[n];
#pragma unroll
            for (int r = 0; r < 4; ++r) {
                int m = m0 + wm * 64 + mi * 16 + fq * 4 + r;
                acat[(size_t)m * 1600 + n] = f2bf(acc[mi][ni][r] + bvs);
            }
        }
    }
}

// ---------------- KAN1: BM=64, BK=64, split-K=8, dbuf, setprio; silu in-reg; bf16 partials ----------------
__global__ __launch_bounds__(256) void kan1_mfma(const ushort* __restrict__ acat,   // [B][1600]
                                                 const ushort* __restrict__ w1aug,  // [64][9216] plain
                                                 const float* __restrict__ grid1,
                                                 ushort* __restrict__ midp) {
    __shared__ ushort As[2][64 * 64];
    __shared__ ushort Bs[2][64 * 64];
    const int tid = threadIdx.x;
    const int w = tid >> 6, lane = tid & 63;
    const int fr = lane & 15, fq = lane >> 4;
    const int m0 = blockIdx.x * 64;
    const int kb = blockIdx.y;                       // 0..7
    const float g0 = grid1[0];
    const float inv_h = 1.0f / (grid1[1] - g0);

    const int srow = tid >> 3, sc = tid & 7;
    const int xr = srow & 7;
    const int lc8 = (sc ^ xr) << 3;
    const ushort* wB0  = w1aug + (size_t)srow * 9216 + lc8;
    const ushort* wB1  = w1aug + (size_t)(srow + 32) * 9216 + lc8;
    const int wpo = srow * 64 + lc8;
    const int wm = w & 1, wn = w >> 1;
    const int cB = kb * 128;                         // silu K base (2 steps of 64)
    const int bB = 1024 + kb * 1024;                 // bases K base (16 steps of 64)

    const ushort* aR0 = acat + (size_t)(m0 + srow) * 1600;
    const ushort* aR1 = acat + (size_t)(m0 + srow + 32) * 1600;

    uint4 sA0[2], sA1[2];
#pragma unroll
    for (int s = 0; s < 2; ++s) {
        sA0[s] = *(const uint4*)(aR0 + cB + s * 64 + sc * 8);
        sA1[s] = *(const uint4*)(aR1 + cB + s * 64 + sc * 8);
    }
    uint xa[16], xb[16];
#pragma unroll
    for (int bs = 0; bs < 16; ++bs) {
        xa[bs] = aR0[cB + bs * 8 + sc];
        xb[bs] = aR1[cB + bs * 8 + sc];
    }

    f32x4 acc[2][2] = {};
    auto stageB = [&](int c, int buf) {
        gl_lds16(wB0 + c, &Bs[buf][tid * 8]);
        gl_lds16(wB1 + c, &Bs[buf][2048 + tid * 8]);
    };
    auto stageAsilu = [&](int s, int buf) {
        uint r0[4] = {sA0[s].x, sA0[s].y, sA0[s].z, sA0[s].w};
        uint r1[4] = {sA1[s].x, sA1[s].y, sA1[s].z, sA1[s].w};
        uint o0[4], o1[4];
#pragma unroll
        for (int p = 0; p < 4; ++p) {
            o0[p] = pack_trunc(siluf_(bf2f(r0[p] & 0xffffu)), siluf_(bf2f(r0[p] >> 16)));
            o1[p] = pack_trunc(siluf_(bf2f(r1[p] & 0xffffu)), siluf_(bf2f(r1[p] >> 16)));
        }
        uint4 q0; q0.x = o0[0]; q0.y = o0[1]; q0.z = o0[2]; q0.w = o0[3];
        uint4 q1; q1.x = o1[0]; q1.y = o1[1]; q1.z = o1[2]; q1.w = o1[3];
        *(uint4*)&As[buf][wpo] = q0;
        *(uint4*)&As[buf][2048 + wpo] = q1;
    };
    auto stageAbases = [&](uint x0u, uint x1u, int buf) {
        uint o0[4], o1[4];
        bases_packed(bf2f(x0u), g0, inv_h, o0);
        bases_packed(bf2f(x1u), g0, inv_h, o1);
        uint4 q0; q0.x = o0[0]; q0.y = o0[1]; q0.z = o0[2]; q0.w = o0[3];
        uint4 q1; q1.x = o1[0]; q1.y = o1[1]; q1.z = o1[2]; q1.w = o1[3];
        *(uint4*)&As[buf][wpo] = q0;
        *(uint4*)&As[buf][2048 + wpo] = q1;
    };
    auto mfma_step = [&](int buf) {
        __builtin_amdgcn_s_setprio(1);               // T5
#pragma unroll
        for (int s2 = 0; s2 < 2; ++s2) {
            short8 af[2], bv[2];
#pragma unroll
            for (int mi = 0; mi < 2; ++mi) {
                int arow = wm * 32 + mi * 16 + fr;
                af[mi] = *(const short8*)(&As[buf][arow * 64 + (((s2 * 4 + fq) ^ (arow & 7)) << 3)]);
            }
#pragma unroll
            for (int ni = 0; ni < 2; ++ni) {
                int brow = wn * 32 + ni * 16 + fr;
                bv[ni] = *(const short8*)(&Bs[buf][brow * 64 + (((s2 * 4 + fq) ^ (brow & 7)) << 3)]);
            }
#pragma unroll
            for (int mi = 0; mi < 2; ++mi)
#pragma unroll
                for (int ni = 0; ni < 2; ++ni)
                    acc[mi][ni] = __builtin_amdgcn_mfma_f32_16x16x32_bf16(af[mi], bv[ni], acc[mi][ni], 0, 0, 0);
        }
        __builtin_amdgcn_s_setprio(0);
    };

    stageB(cB, 0); stageAsilu(0, 0);
    __syncthreads();
    stageB(cB + 64, 1); stageAsilu(1, 1);
    mfma_step(0);
    __syncthreads();
    stageB(bB, 0); stageAbases(xa[0], xb[0], 0);
    mfma_step(1);
#pragma unroll
    for (int bs = 0; bs < 15; ++bs) {
        __syncthreads();
        stageB(bB + (bs + 1) * 64, (bs + 1) & 1);
        stageAbases(xa[bs + 1], xb[bs + 1], (bs + 1) & 1);
        mfma_step(bs & 1);
    }
    __syncthreads();
    mfma_step(1);

    ushort* outp = midp + (size_t)kb * (BATCH * 64);
#pragma unroll
    for (int mi = 0; mi < 2; ++mi)
#pragma unroll
        for (int ni = 0; ni < 2; ++ni)
#pragma unroll
            for (int r = 0; r < 4; ++r)
                outp[(size_t)(m0 + wm * 32 + mi * 16 + fq * 4 + r) * 64 + wn * 32 + ni * 16 + fr] = f2bf(acc[mi][ni][r]);
}

// ---------------- Acat[:,1024:1600] = [silu(mid) | bases(mid)], 8 bf16 partials, 4 elems/thread ----------------
__global__ __launch_bounds__(256) void bs2_kernel(const ushort* __restrict__ midp,
                                                  const float* __restrict__ grid2,
                                                  ushort* __restrict__ acat) {
    int t4 = blockIdx.x * 256 + threadIdx.x;    // over B*16
    if (t4 >= BATCH * 16) return;
    int base = t4 * 4;
    float xs[4] = {0.f, 0.f, 0.f, 0.f};
#pragma unroll
    for (int p = 0; p < 8; ++p) {
        uint2 v = *(const uint2*)(midp + (size_t)p * (BATCH * 64) + base);
        xs[0] += bf2f(v.x & 0xffffu); xs[1] += bf2f(v.x >> 16);
        xs[2] += bf2f(v.y & 0xffffu); xs[3] += bf2f(v.y >> 16);
    }
    int b = base >> 6, i = base & 63;
    float g0 = grid2[0], inv_h = 1.0f / (grid2[1] - g0);
    uint2 sil;
    sil.x = pack2(siluf_(xs[0]), siluf_(xs[1]));
    sil.y = pack2(siluf_(xs[2]), siluf_(xs[3]));
    *(uint2*)&acat[(size_t)b * 1600 + 1024 + i] = sil;
#pragma unroll
    for (int e = 0; e < 4; ++e) {
        uint o[4];
        bases_packed(xs[e], g0, inv_h, o);
        uint4 o4; o4.x = o[0]; o4.y = o[1]; o4.z = o[2]; o4.w = o[3];
        *(uint4*)&acat[(size_t)b * 1600 + 1088 + (i + e) * 8] = o4;
    }
}

// ---------------- fused gate + double-LN + blend ----------------
__device__ __forceinline__ void block_reduce_2(float& a, float& b, float (*red)[4]) {
#pragma unroll
    for (int off = 32; off; off >>= 1) {
        a += __shfl_xor(a, off, 64);
        b += __shfl_xor(b, off, 64);
    }
    int lane = threadIdx.x & 63, wid = threadIdx.x >> 6;
    if (lane == 0) { red[0][wid] = a; red[1][wid] = b; }
    __syncthreads();
    a = red[0][0] + red[0][1] + red[0][2] + red[0][3];
    b = red[1][0] + red[1][1] + red[1][2] + red[1][3];
}

__global__ __launch_bounds__(256) void final2(const ushort* __restrict__ ug,
                                              const ushort* __restrict__ hcb,
                                              const ushort* __restrict__ acat,   // h_prev bf16 at cols 512:1024
                                              const float* __restrict__ ug_g,
                                              const float* __restrict__ ug_beta,
                                              const float* __restrict__ cg,
                                              const float* __restrict__ cb,
                                              float* __restrict__ out) {
    int row = blockIdx.x, tid = threadIdx.x;
    __shared__ float rA[2][4], rB[2][4], rC[2][4];
    float u0 = bf2f((uint)ug[(size_t)row * 512 + tid]);
    float u1 = bf2f((uint)ug[(size_t)row * 512 + tid + 256]);
    float h0 = bf2f((uint)hcb[(size_t)row * 512 + tid]);
    float h1 = bf2f((uint)hcb[(size_t)row * 512 + tid + 256]);
    float hp0 = bf2f((uint)acat[(size_t)row * 1600 + 512 + tid]);
    float hp1 = bf2f((uint)acat[(size_t)row * 1600 + 768 + tid]);
    float s = u0 + u1, ss = u0 * u0 + u1 * u1;
    block_reduce_2(s, ss, rA);
    float mu = s * (1.0f / 512.0f);
    float var = ss * (1.0f / 512.0f) - mu * mu;
    float r = rsqrtf(var + 1e-5f);
    float uu0 = sigmoidf_((u0 - mu) * r * ug_g[tid] + ug_beta[tid]);
    float uu1 = sigmoidf_((u1 - mu) * r * ug_g[tid + 256] + ug_beta[tid + 256]);
    float cg0 = cg[tid], cg1 = cg[tid + 256], cb0 = cb[tid], cb1 = cb[tid + 256];
    float s2 = h0 + h1, ss2 = h0 * h0 + h1 * h1;
    block_reduce_2(s2, ss2, rB);
    float mu2 = s2 * (1.0f / 512.0f);
    float var2 = ss2 * (1.0f / 512.0f) - mu2 * mu2;
    float r2 = rsqrtf(var2 + 1e-5f);
    float w0 = (h0 - mu2) * r2 * cg0 + cb0;
    float w1 = (h1 - mu2) * r2 * cg1 + cb1;
    float s3 = w0 + w1, ss3 = w0 * w0 + w1 * w1;
    block_reduce_2(s3, ss3, rC);
    float mu3 = s3 * (1.0f / 512.0f);
    float var3 = ss3 * (1.0f / 512.0f) - mu3 * mu3;
    float r3 = rsqrtf(var3 + 1e-5f);
    float c0 = siluf_((w0 - mu3) * r3 * cg0 + cb0);
    float c1 = siluf_((w1 - mu3) * r3 * cg1 + cb1);
    size_t o0 = (size_t)row * 512 + tid, o1 = o0 + 256;
    out[o0] = (1.0f - uu0) * hp0 + uu0 * c0;
    out[o1] = (1.0f - uu1) * hp1 + uu1 * c1;
}

extern "C" void kernel_launch(void* const* d_in, const int* in_sizes, int n_in,
                              void* d_out, int out_size, void* d_ws, size_t ws_size,
                              hipStream_t stream) {
    const float* x        = (const float*)d_in[0];
    const float* h_prev   = (const float*)d_in[1];
    const float* ip_w     = (const float*)d_in[2];
    const float* ip_b     = (const float*)d_in[3];
    // d_in[4..7] rg_* : dead (reset gate unused in h_t)
    const float* ug_w     = (const float*)d_in[8];
    const float* ug_b     = (const float*)d_in[9];
    const float* ug_g     = (const float*)d_in[10];
    const float* ug_beta  = (const float*)d_in[11];
    const float* k1_base  = (const float*)d_in[12];
    const float* k1_spline= (const float*)d_in[13];
    const float* k1_scaler= (const float*)d_in[14];
    const float* grid1    = (const float*)d_in[15];
    const float* k2_base  = (const float*)d_in[16];
    const float* k2_spline= (const float*)d_in[17];
    const float* k2_scaler= (const float*)d_in[18];
    const float* grid2    = (const float*)d_in[19];
    const float* cn_g     = (const float*)d_in[20];
    const float* cn_b     = (const float*)d_in[21];
    const float* rp_w     = (const float*)d_in[22];
    const float* rp_b     = (const float*)d_in[23];
    float* out = (float*)d_out;
    char* W = (char*)d_ws;

    ushort* Acat    = (ushort*)(W);                   // 52,428,800 B  [B][1600]
    ushort* ug_bf   = (ushort*)(W + 52428800);        // 16,777,216 B  [B][512]
    ushort* midp    = (ushort*)(W + 69206016);        // 16,777,216 B  8x[B][64] bf16
    ushort* hc_bf   = (ushort*)(W + 102760448);       // 16,777,216 B  [B][512]
    ushort* ipw_bf  = (ushort*)(W + 136314880);       //    262,144 B
    ushort* ugw_bf  = (ushort*)(W + 136577024);       //  1,048,576 B
    ushort* wcat    = (ushort*)(W + 137625600);       //  1,638,400 B  [512][1600]
    ushort* w1aug   = (ushort*)(W + 139264000);       //  1,179,648 B  (plain)

    // --- prep: h-copy + all weight conversions in ONE launch ---
    hipLaunchKernelGGL(prep_all, dim3(12160), dim3(256), 0, stream,
                       h_prev, ip_w, ug_w, rp_w, k2_base, k2_spline, k2_scaler,
                       k1_base, k1_spline, k1_scaler,
                       Acat, ipw_bf, ugw_bf, wcat, w1aug);

    // --- Acat[:,0:512] = bf16(x @ ip_w.T + ip_b) ---
    hipLaunchKernelGGL(gemm_ip, dim3(BATCH / 128, 4), dim3(256), 0, stream,
                       x, ipw_bf, ip_b, Acat);

    // --- ug_pre = bf16(comb @ ug_w.T + ug_b) ---
    hipLaunchKernelGGL(gemm_mfma, dim3(BATCH / 128, 4), dim3(256), 0, stream,
                       Acat, 1600, ugw_bf, 1024, ug_b, ug_bf, 512, 1024);

    // --- KAN1 (split-K=8, silu in-register, bf16 partials) -> midp -> Acat[:,1024:1600] ---
    hipLaunchKernelGGL(kan1_mfma, dim3(BATCH / 64, 8), dim3(256), 0, stream,
                       Acat, w1aug, grid1, midp);
    hipLaunchKernelGGL(bs2_kernel, dim3(BATCH * 16 / 256), dim3(256), 0, stream, midp, grid2, Acat);

    // --- hc = bf16(Acat @ Wcat.T + rp_b)  (residual + KAN2 in one GEMM) ---
    hipLaunchKernelGGL(gemm_mfma, dim3(BATCH / 128, 4), dim3(256), 0, stream,
                       Acat, 1600, wcat, 1600, rp_b, hc_bf, 512, 1600);

    // --- h_t ---
    hipLaunchKernelGGL(final2, dim3(BATCH), dim3(256), 0, stream, ug_bf, hc_bf, Acat, ug_g, ug_beta, cn_g, cn_b, out);
}